// Round 1
// baseline (2300.738 us; speedup 1.0000x reference)
//
#include <hip/hip_runtime.h>

// SppPooling: out[b,gx,gy,:] = sum over nodes n in graph b with bin (gx,gy) of
//             features[n,:] / div[n]
// N=2e6, D=128, G=8, B=64. Nodes are contiguous per graph (graph_id = repeat),
// so each graph's output slab (8*8*128 fp32 = 32 KB) fits in LDS: accumulate
// per-chunk in LDS (ds_add_f32), flush once with global fp32 atomics.

#define GBINS 8
#define DIM 128
#define TILE (GBINS * GBINS * DIM)   // 8192 floats = 32 KB LDS
#define CHUNKS 40                    // blocks per graph -> 64*40 = 2560 blocks
#define NBLOCK 256                   // 4 waves; one node per wave per iter
#define NWAVES (NBLOCK / 64)

__global__ __launch_bounds__(NBLOCK) void spp_pool_kernel(
    const float* __restrict__ features,
    const int*   __restrict__ xy,     // [N,3]: binx, biny, div
    const int*   __restrict__ bnn,    // [B] batch_num_nodes
    float*       __restrict__ out,    // [B, 8, 8, 128], pre-zeroed
    int N, int B)
{
    __shared__ float tile[TILE];
    for (int i = threadIdx.x; i < TILE; i += NBLOCK) tile[i] = 0.0f;
    __syncthreads();

    const int g = blockIdx.x / CHUNKS;   // graph id
    const int c = blockIdx.x % CHUNKS;   // chunk within graph

    // start offset of graph g (B=64: short uniform scalar loop, L2/scalar-cached)
    int start = 0;
    for (int i = 0; i < g; ++i) start += bnn[i];
    const int cnt  = bnn[g];
    const int per  = (cnt + CHUNKS - 1) / CHUNKS;
    const int nbeg = start + c * per;
    const int nend = min(start + cnt, nbeg + per);

    const int wave = threadIdx.x >> 6;
    const int lane = threadIdx.x & 63;

    // One node per wave per iteration: 64 lanes read a 512 B feature row
    // (two coalesced 256 B dword loads: cols lane and lane+64), scale by
    // 1/div, LDS-atomic into the seg row. lane-contiguous addresses ->
    // 2-way bank aliasing only (free on gfx950).
    for (int n = nbeg + wave; n < nend; n += NWAVES) {
        const int x = xy[3 * n];
        const int y = xy[3 * n + 1];
        const int d = xy[3 * n + 2];
        const float inv = 1.0f / (float)d;
        const int segbase = (x * GBINS + y) * DIM;
        const float* __restrict__ frow = features + (size_t)n * DIM;
        const float v0 = frow[lane]      * inv;
        const float v1 = frow[lane + 64] * inv;
        atomicAdd(&tile[segbase + lane],      v0);   // ds_add_f32
        atomicAdd(&tile[segbase + lane + 64], v1);
    }
    __syncthreads();

    // Flush 32 KB tile to global: 8192 atomics/block, ~21M total (vs 256M
    // for a fully-naive scatter). Coalesced: consecutive lanes ->
    // consecutive addresses. Target region is 2 MB -> L2-resident.
    float* __restrict__ og = out + (size_t)g * TILE;
    for (int i = threadIdx.x; i < TILE; i += NBLOCK) {
        unsafeAtomicAdd(&og[i], tile[i]);            // global_atomic_add_f32
    }
}

extern "C" void kernel_launch(void* const* d_in, const int* in_sizes, int n_in,
                              void* d_out, int out_size, void* d_ws, size_t ws_size,
                              hipStream_t stream) {
    const float* features = (const float*)d_in[0];
    const int*   xy       = (const int*)d_in[1];
    const int*   bnn      = (const int*)d_in[2];
    float*       out      = (float*)d_out;

    const int N = in_sizes[1] / 3;
    const int B = in_sizes[2];

    // d_out is re-poisoned to 0xAA before every timed launch -> must zero it.
    hipMemsetAsync(d_out, 0, (size_t)out_size * sizeof(float), stream);

    dim3 grid(B * CHUNKS), block(NBLOCK);
    spp_pool_kernel<<<grid, block, 0, stream>>>(features, xy, bnn, out, N, B);
}